// Round 13
// baseline (158.510 us; speedup 1.0000x reference)
//
#include <hip/hip_runtime.h>
#include <hip/hip_bf16.h>
#include <cstdint>

#define BATCH 4
#define SEQ   2048
#define DIN   1024
#define DOUT  1024
#define SCALE 0.03125f   // 1/sqrt(1024)

typedef unsigned short u16;
typedef float  f32x4  __attribute__((ext_vector_type(4)));
typedef __bf16 bf16x8 __attribute__((ext_vector_type(8)));

__device__ __forceinline__ u16 f2bf(float f) {
    unsigned u = __float_as_uint(f);
    unsigned r = 0x7fffu + ((u >> 16) & 1u);
    return (u16)((u + r) >> 16);
}

__device__ __forceinline__ f32x4 mfma16(bf16x8 a, bf16x8 b, f32x4 c) {
    return __builtin_amdgcn_mfma_f32_16x16x32_bf16(a, b, c, 0, 0, 0);
}

__device__ __forceinline__ void gl_lds16(const u16* g, u16* l) {
    __builtin_amdgcn_global_load_lds(
        (const __attribute__((address_space(1))) unsigned int*)g,
        (__attribute__((address_space(3))) unsigned int*)l, 16, 0, 0);
}

#define BAR    asm volatile("s_barrier" ::: "memory")
#define VMCNT3 asm volatile("s_waitcnt vmcnt(3)" ::: "memory")
#define VMCNT4 asm volatile("s_waitcnt vmcnt(4)" ::: "memory")
#define VMCNT0 asm volatile("s_waitcnt vmcnt(0)" ::: "memory")
#define LGKM0  asm volatile("s_waitcnt lgkmcnt(0)" ::: "memory")

// ------- fused fp32 -> bf16 conversion (x | wq | wk | wv) + rowsum zero ----
__global__ __launch_bounds__(256) void cvt_all(const float* __restrict__ x,
                                               const float* __restrict__ wq,
                                               const float* __restrict__ wk,
                                               const float* __restrict__ wv,
                                               u16* __restrict__ dst,
                                               float* __restrict__ rowsum) {
    const size_t NX = (size_t)BATCH * SEQ * DIN;
    size_t gt = (size_t)blockIdx.x * 256 + threadIdx.x;
    if (gt < 1024) {  // zero rowsum[8192] (8 floats/thread)
        f32x4 z = {0.f, 0.f, 0.f, 0.f};
        *(f32x4*)(rowsum + gt * 8) = z;
        *(f32x4*)(rowsum + gt * 8 + 4) = z;
    }
    size_t e = gt * 8;
    const float* src;
    size_t off;
    if (e < NX) { src = x; off = e; }
    else {
        size_t r = e - NX;
        int w = (int)(r >> 20);
        src = (w == 0) ? wq : (w == 1) ? wk : wv;
        off = r & ((1u << 20) - 1);
    }
    f32x4 a = *(const f32x4*)(src + off);
    f32x4 b = *(const f32x4*)(src + off + 4);
    uint4 o;
    o.x = (unsigned)f2bf(a[0]) | ((unsigned)f2bf(a[1]) << 16);
    o.y = (unsigned)f2bf(a[2]) | ((unsigned)f2bf(a[3]) << 16);
    o.z = (unsigned)f2bf(b[0]) | ((unsigned)f2bf(b[1]) << 16);
    o.w = (unsigned)f2bf(b[2]) | ((unsigned)f2bf(b[3]) << 16);
    *(uint4*)(dst + e) = o;
}

// ======================================================================
// Staging: N-row x 64-col bf16 units (128B rows), linear rows, row-XOR
// swizzle (byte ^= (row&7)<<4) applied inverse on the global source.
// ======================================================================
__device__ __forceinline__ void stg128(const u16* __restrict__ g, int ld,
                                       u16* unit, int tid) {
#pragma unroll
    for (int i = 0; i < 2; i++) {
        int D = (i * 512 + tid) * 16;
        int r = D >> 7, w = D & 127;
        int gcol = (w ^ ((r & 7) << 4)) >> 1;
        gl_lds16(g + (size_t)r * ld + gcol, unit + (i * 512 + (tid >> 6) * 64) * 8);
    }
}

__device__ __forceinline__ void stg192(const u16* __restrict__ g, int ld,
                                       u16* unit, int tid) {
#pragma unroll
    for (int i = 0; i < 3; i++) {
        int D = (i * 512 + tid) * 16;
        int r = D >> 7, w = D & 127;
        int gcol = (w ^ ((r & 7) << 4)) >> 1;
        gl_lds16(g + (size_t)r * ld + gcol, unit + (i * 512 + (tid >> 6) * 64) * 8);
    }
}

__device__ __forceinline__ void rd4(const u16* unit, int rowbase, int l15, int l4,
                                    bf16x8 f[4][2]) {
    const char* u = (const char*)unit;
#pragma unroll
    for (int i = 0; i < 4; i++) {
        int row = rowbase + i * 16 + l15;
#pragma unroll
        for (int kk = 0; kk < 2; kk++)
            f[i][kk] = *(const bf16x8*)(u + row * 128 +
                                        ((kk * 64 + l4 * 16) ^ ((row & 7) << 4)));
    }
}

__device__ __forceinline__ void rd3(const u16* unit, int rowbase, int l15, int l4,
                                    bf16x8 f[3][2]) {
    const char* u = (const char*)unit;
#pragma unroll
    for (int i = 0; i < 3; i++) {
        int row = rowbase + i * 16 + l15;
#pragma unroll
        for (int kk = 0; kk < 2; kk++)
            f[i][kk] = *(const bf16x8*)(u + row * 128 +
                                        ((kk * 64 + l4 * 16) ^ ((row & 7) << 4)));
    }
}

__device__ __forceinline__ void rd2k(const u16* unit, int row0, int l15, int l4,
                                     bf16x8 f[2]) {
    const char* u = (const char*)unit;
    int row = row0 + l15;
#pragma unroll
    for (int kk = 0; kk < 2; kk++)
        f[kk] = *(const bf16x8*)(u + row * 128 +
                                 ((kk * 64 + l4 * 16) ^ ((row & 7) << 4)));
}

// ======================================================================
// G64: 128x128 tile, BK=64, 8 waves (2M x 4N), per-wave 64x32, 64KB LDS.
// ======================================================================
__device__ __forceinline__ void g64_body(u16* lds, const u16* __restrict__ Ag,
                                         int lda, const u16* __restrict__ Bg,
                                         int ldb, int nkt, int wm, int wn,
                                         int l15, int l4, int tid,
                                         f32x4 acc[4][2]) {
    bf16x8 a[4][2], b0[2], b1[2];
    u16* A0 = lds;          u16* B0 = lds + 8192;
    u16* A1 = lds + 16384;  u16* B1 = lds + 24576;
    stg128(Ag, lda, A0, tid);      stg128(Bg, ldb, B0, tid);
    stg128(Ag + 64, lda, A1, tid); stg128(Bg + 64, ldb, B1, tid);
    VMCNT4; BAR;
    for (int t = 0; t < nkt; t += 2) {
        {
            const int k2 = ((t + 2 < nkt) ? t + 2 : nkt - 1) * 64;
            rd4(A0, wm * 64, l15, l4, a);
            rd2k(B0, wn * 32, l15, l4, b0);
            rd2k(B0, wn * 32 + 16, l15, l4, b1);
            BAR;
            __builtin_amdgcn_s_setprio(1);
#pragma unroll
            for (int kk = 0; kk < 2; kk++)
#pragma unroll
                for (int mi = 0; mi < 4; mi++)
                    acc[mi][0] = mfma16(a[mi][kk], b0[kk], acc[mi][0]);
            __builtin_amdgcn_s_setprio(0);
            LGKM0; BAR;
            stg128(Ag + k2, lda, A0, tid);
            stg128(Bg + k2, ldb, B0, tid);
            VMCNT4; BAR;
            __builtin_amdgcn_s_setprio(1);
#pragma unroll
            for (int kk = 0; kk < 2; kk++)
#pragma unroll
                for (int mi = 0; mi < 4; mi++)
                    acc[mi][1] = mfma16(a[mi][kk], b1[kk], acc[mi][1]);
            __builtin_amdgcn_s_setprio(0);
            BAR;
        }
        {
            const int k3 = ((t + 3 < nkt) ? t + 3 : nkt - 1) * 64;
            rd4(A1, wm * 64, l15, l4, a);
            rd2k(B1, wn * 32, l15, l4, b0);
            rd2k(B1, wn * 32 + 16, l15, l4, b1);
            BAR;
            __builtin_amdgcn_s_setprio(1);
#pragma unroll
            for (int kk = 0; kk < 2; kk++)
#pragma unroll
                for (int mi = 0; mi < 4; mi++)
                    acc[mi][0] = mfma16(a[mi][kk], b0[kk], acc[mi][0]);
            __builtin_amdgcn_s_setprio(0);
            LGKM0; BAR;
            stg128(Ag + k3, lda, A1, tid);
            stg128(Bg + k3, ldb, B1, tid);
            VMCNT4; BAR;
            __builtin_amdgcn_s_setprio(1);
#pragma unroll
            for (int kk = 0; kk < 2; kk++)
#pragma unroll
                for (int mi = 0; mi < 4; mi++)
                    acc[mi][1] = mfma16(a[mi][kk], b1[kk], acc[mi][1]);
            __builtin_amdgcn_s_setprio(0);
            BAR;
        }
    }
    VMCNT0;
}

// ======================================================================
// QKV: C[8192,3072] = X * Wcat^T.  256x192 tile, BK=64, 8 waves (2Mx4N),
// per-wave 128x48, acc[8][3].  512 tiles = exactly 2 per block.
// V fragments -> direct transposed uint2 stores into vt[b][d][s].
// ======================================================================
#define QKV_PH0(AU, BU, ANX0, ANX1, K1)                                      \
    rd4((AU), 0, l15, l4, a);                                                \
    rd3((BU), wn * 48, l15, l4, b);                                          \
    stg128(Ag + (K1), DIN, (ANX0), tid);                                     \
    stg128(Ag + (size_t)128 * DIN + (K1), DIN, (ANX1), tid);                 \
    BAR;                                                                     \
    __builtin_amdgcn_s_setprio(1);                                           \
    _Pragma("unroll") for (int kk = 0; kk < 2; kk++)                         \
    _Pragma("unroll") for (int mi = 0; mi < 4; mi++)                         \
    _Pragma("unroll") for (int ni = 0; ni < 3; ni++)                         \
        acc[mi][ni] = mfma16(a[mi][kk], b[ni][kk], acc[mi][ni]);             \
    __builtin_amdgcn_s_setprio(0);                                           \
    BAR;

#define QKV_PH1(AU, BCUR, K2)                                                \
    rd4((AU), 64, l15, l4, a);                                               \
    stg192(Bg + (K2), DIN, (BCUR), tid);                                     \
    VMCNT3; BAR;                                                             \
    __builtin_amdgcn_s_setprio(1);                                           \
    _Pragma("unroll") for (int kk = 0; kk < 2; kk++)                         \
    _Pragma("unroll") for (int mi = 0; mi < 4; mi++)                         \
    _Pragma("unroll") for (int ni = 0; ni < 3; ni++)                         \
        acc[4 + mi][ni] = mfma16(a[mi][kk], b[ni][kk], acc[4 + mi][ni]);     \
    __builtin_amdgcn_s_setprio(0);                                           \
    BAR;

__global__ __launch_bounds__(512) void qkv_gemm192(const u16* __restrict__ xb,
                                                   const u16* __restrict__ wb,
                                                   u16* __restrict__ qkv,
                                                   u16* __restrict__ vt) {
    extern __shared__ __align__(16) u16 lds[];
    const int tid = threadIdx.x, lane = tid & 63, wid = tid >> 6;
    const int wm = wid >> 2, wn = wid & 3;
    const int l15 = lane & 15, l4 = lane >> 4;

    u16* A00 = lds;          u16* A01 = lds + 8192;
    u16* A10 = lds + 16384;  u16* A11 = lds + 24576;
    u16* B0  = lds + 32768;  u16* B1  = lds + 45056;
    u16* Ar0 = lds + wm * 8192;
    u16* Ar1 = lds + 16384 + wm * 8192;

    for (int tile = blockIdx.x; tile < 512; tile += 256) {
        const int wg = (tile & 7) * 64 + (tile >> 3);  // bijective XCD swizzle
        const int mt = wg & 31, nt = wg >> 5;
        const int m0 = mt * 256, n0 = nt * 192;
        const u16* Ag = xb + (size_t)m0 * DIN;
        const u16* Bg = wb + (size_t)n0 * DIN;
        f32x4 acc[8][3] = {};
        bf16x8 a[4][2], b[3][2];

        stg128(Ag, DIN, A00, tid);
        stg128(Ag + (size_t)128 * DIN, DIN, A01, tid);
        stg192(Bg, DIN, B0, tid);
        stg192(Bg + 64, DIN, B1, tid);
        VMCNT3;
        BAR;

        for (int i = 0; i < 8; i++) {
            const int k1 = (2 * i + 1) * 64;
            const int k2 = ((2 * i + 2 < 16) ? 2 * i + 2 : 15) * 64;
            const int k3 = ((2 * i + 3 < 16) ? 2 * i + 3 : 15) * 64;
            QKV_PH0(Ar0, B0, A10, A11, k1)
            QKV_PH1(Ar0, B0, k2)
            QKV_PH0(Ar1, B1, A00, A01, k2)
            QKV_PH1(Ar1, B1, k3)
        }
        VMCNT0;

#pragma unroll
        for (int ai = 0; ai < 8; ai++)
#pragma unroll
            for (int bj = 0; bj < 3; bj++) {
                const int colb = n0 + wn * 48 + bj * 16;   // 16-aligned, uniform
                const int row = m0 + wm * 128 + ai * 16 + l4 * 4;
                if (colb >= 2 * DOUT) {
                    int d = colb + l15 - 2 * DOUT;
                    int batch = row >> 11, s0 = row & 2047;
                    uint2 o;
                    o.x = (unsigned)f2bf(acc[ai][bj][0]) |
                          ((unsigned)f2bf(acc[ai][bj][1]) << 16);
                    o.y = (unsigned)f2bf(acc[ai][bj][2]) |
                          ((unsigned)f2bf(acc[ai][bj][3]) << 16);
                    *(uint2*)&vt[(size_t)batch * DOUT * SEQ + (size_t)d * SEQ + s0] = o;
                } else {
                    const int wsel = colb >> 10;
                    u16* Op = qkv + (size_t)wsel * ((size_t)BATCH * SEQ * DOUT);
                    const int col = (colb & 1023) + l15;
#pragma unroll
                    for (int rr = 0; rr < 4; rr++)
                        Op[(size_t)(row + rr) * DOUT + col] = f2bf(acc[ai][bj][rr]);
                }
            }
    }
}

// ---------------- QK^T + fused exp/row-sum (no-max softmax) ----------------
__global__ __launch_bounds__(512, 4) void qk_g64(const u16* __restrict__ qg,
                                                 const u16* __restrict__ kg,
                                                 u16* __restrict__ sg,
                                                 float* __restrict__ rowsum) {
    extern __shared__ __align__(16) u16 lds[];
    const int bxx = blockIdx.x, batch = blockIdx.y;
    int mt = 0, base = 0;
#pragma unroll 16
    for (int m = 0; m < 16; m++) {
        int c = m + 1;
        if (bxx < base + c) { mt = m; break; }
        base += c;
    }
    const int nt = bxx - base;
    const int m0 = mt * 128, n0 = nt * 128;
    const int tid = threadIdx.x, lane = tid & 63;
    const int wm = (tid >> 6) >> 2, wn = (tid >> 6) & 3;
    const int l15 = lane & 15, l4 = lane >> 4;
    const size_t bo = (size_t)batch * SEQ * DOUT;

    f32x4 acc[4][2] = {};
    g64_body(lds, qg + bo + (size_t)m0 * DOUT, DOUT,
             kg + bo + (size_t)n0 * DOUT, DOUT, 16,
             wm, wn, l15, l4, tid, acc);

    u16* Sp = sg + (size_t)batch * SEQ * SEQ;
    float* Rs = rowsum + (size_t)batch * SEQ;
#pragma unroll
    for (int ai = 0; ai < 4; ai++)
#pragma unroll
        for (int rr = 0; rr < 4; rr++) {
            int q = m0 + wm * 64 + ai * 16 + l4 * 4 + rr;
            float rp = 0.f;
#pragma unroll
            for (int bj = 0; bj < 2; bj++) {
                int kc = n0 + wn * 32 + bj * 16 + l15;
                float p = (kc <= q) ? __expf(acc[ai][bj][rr] * SCALE) : 0.f;
                rp += p;
                Sp[(size_t)q * SEQ + kc] = f2bf(p);
            }
#pragma unroll
            for (int off = 8; off >= 1; off >>= 1) rp += __shfl_xor(rp, off, 16);
            if (l15 == 0) atomicAdd(&Rs[q], rp);
        }
}

// ---------------- PV: 512 blocks, longest-first, 2/CU co-residency ---------
__global__ __launch_bounds__(512, 4) void pv_g64(const u16* __restrict__ pg,
                                                 const u16* __restrict__ vtg,
                                                 const float* __restrict__ rowsum,
                                                 float* __restrict__ og) {
    extern __shared__ __align__(16) u16 lds[];
    const int mt = 15 - (int)blockIdx.x;   // longest-first
    const int n0 = blockIdx.y * 128, batch = blockIdx.z;
    const int m0 = mt * 128;
    const int nkt = (mt + 1) * 2;
    const int tid = threadIdx.x, lane = tid & 63;
    const int wm = (tid >> 6) >> 2, wn = (tid >> 6) & 3;
    const int l15 = lane & 15, l4 = lane >> 4;
    const u16* Pb = pg + (size_t)batch * SEQ * SEQ;
    const u16* Vb = vtg + (size_t)batch * DOUT * SEQ + (size_t)n0 * SEQ;
    const float* Rs = rowsum + (size_t)batch * SEQ;
    float* Ob = og + (size_t)batch * SEQ * DOUT;

    f32x4 acc[4][2] = {};
    g64_body(lds, Pb + (size_t)m0 * SEQ, SEQ, Vb, SEQ, nkt,
             wm, wn, l15, l4, tid, acc);

#pragma unroll
    for (int ai = 0; ai < 4; ai++)
#pragma unroll
        for (int rr = 0; rr < 4; rr++) {
            int q = m0 + wm * 64 + ai * 16 + l4 * 4 + rr;
            float inv = 1.0f / Rs[q];
#pragma unroll
            for (int bj = 0; bj < 2; bj++) {
                int d = n0 + wn * 32 + bj * 16 + l15;
                Ob[(size_t)q * DOUT + d] = acc[ai][bj][rr] * inv;
            }
        }
}

extern "C" void kernel_launch(void* const* d_in, const int* in_sizes, int n_in,
                              void* d_out, int out_size, void* d_ws, size_t ws_size,
                              hipStream_t stream) {
    const float* x  = (const float*)d_in[0];
    const float* wq = (const float*)d_in[1];
    const float* wk = (const float*)d_in[2];
    const float* wv = (const float*)d_in[3];
    float* out = (float*)d_out;

    const size_t NX  = (size_t)BATCH * SEQ * DIN;  // 8M elems
    const size_t NWT = (size_t)DOUT * DIN;         // 1M elems
    u16* xb  = (u16*)d_ws;            // 16 MB
    u16* wb  = xb + NX;               // 6 MB (wq|wk|wv = Wcat[3072][1024])
    u16* qkv = wb + 3 * NWT;          // 48 MB (q,k; v slot unused)
    u16* vt  = qkv + 3 * NX;          // 16 MB (V^T, written directly by qkv)
    u16* sb  = vt + NX;               // 33.5 MB P' (bf16)
    float* rowsum = (float*)(sb + (size_t)BATCH * SEQ * SEQ);  // 32 KB

    cvt_all<<<(NX + 3 * NWT) / 8 / 256, 256, 0, stream>>>(x, wq, wk, wv, xb, rowsum);

    (void)hipFuncSetAttribute((const void*)qkv_gemm192,
                              hipFuncAttributeMaxDynamicSharedMemorySize, 114688);
    (void)hipFuncSetAttribute((const void*)qk_g64,
                              hipFuncAttributeMaxDynamicSharedMemorySize, 65536);
    (void)hipFuncSetAttribute((const void*)pv_g64,
                              hipFuncAttributeMaxDynamicSharedMemorySize, 65536);

    qkv_gemm192<<<dim3(256), dim3(512), 114688, stream>>>(xb, wb, qkv, vt);

    qk_g64<<<dim3(136, BATCH), dim3(512), 65536, stream>>>(qkv, qkv + NX, sb, rowsum);

    pv_g64<<<dim3(16, 8, 4), dim3(512), 65536, stream>>>(sb, vt, rowsum, out);
}

// Round 14
// 147.250 us; speedup vs baseline: 1.0765x; 1.0765x over previous
//
#include <hip/hip_runtime.h>
#include <hip/hip_bf16.h>
#include <cstdint>

#define BATCH 4
#define SEQ   2048
#define DIN   1024
#define DOUT  1024
#define SCALE 0.03125f   // 1/sqrt(1024)

typedef unsigned short u16;
typedef float  f32x4  __attribute__((ext_vector_type(4)));
typedef __bf16 bf16x8 __attribute__((ext_vector_type(8)));

__device__ __forceinline__ u16 f2bf(float f) {
    unsigned u = __float_as_uint(f);
    unsigned r = 0x7fffu + ((u >> 16) & 1u);
    return (u16)((u + r) >> 16);
}

__device__ __forceinline__ f32x4 mfma16(bf16x8 a, bf16x8 b, f32x4 c) {
    return __builtin_amdgcn_mfma_f32_16x16x32_bf16(a, b, c, 0, 0, 0);
}

__device__ __forceinline__ void gl_lds16(const u16* g, u16* l) {
    __builtin_amdgcn_global_load_lds(
        (const __attribute__((address_space(1))) unsigned int*)g,
        (__attribute__((address_space(3))) unsigned int*)l, 16, 0, 0);
}

#define BAR    asm volatile("s_barrier" ::: "memory")
#define VMCNT3 asm volatile("s_waitcnt vmcnt(3)" ::: "memory")
#define VMCNT8 asm volatile("s_waitcnt vmcnt(8)" ::: "memory")
#define VMCNT0 asm volatile("s_waitcnt vmcnt(0)" ::: "memory")
#define LGKM0  asm volatile("s_waitcnt lgkmcnt(0)" ::: "memory")

// ------- fused fp32 -> bf16 conversion (x | wq | wk | wv) + rowsum zero ----
__global__ __launch_bounds__(256) void cvt_all(const float* __restrict__ x,
                                               const float* __restrict__ wq,
                                               const float* __restrict__ wk,
                                               const float* __restrict__ wv,
                                               u16* __restrict__ dst,
                                               float* __restrict__ rowsum) {
    const size_t NX = (size_t)BATCH * SEQ * DIN;
    size_t gt = (size_t)blockIdx.x * 256 + threadIdx.x;
    if (gt < 1024) {
        f32x4 z = {0.f, 0.f, 0.f, 0.f};
        *(f32x4*)(rowsum + gt * 8) = z;
        *(f32x4*)(rowsum + gt * 8 + 4) = z;
    }
    size_t e = gt * 8;
    const float* src;
    size_t off;
    if (e < NX) { src = x; off = e; }
    else {
        size_t r = e - NX;
        int w = (int)(r >> 20);
        src = (w == 0) ? wq : (w == 1) ? wk : wv;
        off = r & ((1u << 20) - 1);
    }
    f32x4 a = *(const f32x4*)(src + off);
    f32x4 b = *(const f32x4*)(src + off + 4);
    uint4 o;
    o.x = (unsigned)f2bf(a[0]) | ((unsigned)f2bf(a[1]) << 16);
    o.y = (unsigned)f2bf(a[2]) | ((unsigned)f2bf(a[3]) << 16);
    o.z = (unsigned)f2bf(b[0]) | ((unsigned)f2bf(b[1]) << 16);
    o.w = (unsigned)f2bf(b[2]) | ((unsigned)f2bf(b[3]) << 16);
    *(uint4*)(dst + e) = o;
}

// ======================================================================
// Staging: 128-row x 64-col bf16 units (128B rows), linear rows, row-XOR
// swizzle (byte ^= (row&7)<<4) applied inverse on the global source.
// ======================================================================
__device__ __forceinline__ void stg128(const u16* __restrict__ g, int ld,
                                       u16* unit, int tid) {
#pragma unroll
    for (int i = 0; i < 2; i++) {
        int D = (i * 512 + tid) * 16;
        int r = D >> 7, w = D & 127;
        int gcol = (w ^ ((r & 7) << 4)) >> 1;
        gl_lds16(g + (size_t)r * ld + gcol, unit + (i * 512 + (tid >> 6) * 64) * 8);
    }
}

__device__ __forceinline__ void stg192(const u16* __restrict__ g, int ld,
                                       u16* unit, int tid) {
#pragma unroll
    for (int i = 0; i < 3; i++) {
        int D = (i * 512 + tid) * 16;
        int r = D >> 7, w = D & 127;
        int gcol = (w ^ ((r & 7) << 4)) >> 1;
        gl_lds16(g + (size_t)r * ld + gcol, unit + (i * 512 + (tid >> 6) * 64) * 8);
    }
}

// 256-thread variant: 4 iters fill one 16KB unit
__device__ __forceinline__ void stg4(const u16* __restrict__ g, int ld,
                                     u16* unit, int tid) {
#pragma unroll
    for (int i = 0; i < 4; i++) {
        int D = (i * 256 + tid) * 16;
        int r = D >> 7, w = D & 127;
        int gcol = (w ^ ((r & 7) << 4)) >> 1;
        gl_lds16(g + (size_t)r * ld + gcol, unit + (i * 256 + (tid >> 6) * 64) * 8);
    }
}

__device__ __forceinline__ void rd4(const u16* unit, int rowbase, int l15, int l4,
                                    bf16x8 f[4][2]) {
    const char* u = (const char*)unit;
#pragma unroll
    for (int i = 0; i < 4; i++) {
        int row = rowbase + i * 16 + l15;
#pragma unroll
        for (int kk = 0; kk < 2; kk++)
            f[i][kk] = *(const bf16x8*)(u + row * 128 +
                                        ((kk * 64 + l4 * 16) ^ ((row & 7) << 4)));
    }
}

__device__ __forceinline__ void rd3(const u16* unit, int rowbase, int l15, int l4,
                                    bf16x8 f[3][2]) {
    const char* u = (const char*)unit;
#pragma unroll
    for (int i = 0; i < 3; i++) {
        int row = rowbase + i * 16 + l15;
#pragma unroll
        for (int kk = 0; kk < 2; kk++)
            f[i][kk] = *(const bf16x8*)(u + row * 128 +
                                        ((kk * 64 + l4 * 16) ^ ((row & 7) << 4)));
    }
}

// ======================================================================
// G4: 128x128 tile, BK=64, 4 waves (2M x 2N), per-wave 64x64, 64KB LDS,
// 256 threads -> 2 blocks/CU.  0.5 ds_reads per MFMA (vs 0.75 in 8-wave).
// Same proven 2-phase schedule; load batches are 8 -> vmcnt(8).
// ======================================================================
__device__ __forceinline__ void g4_body(u16* lds, const u16* __restrict__ Ag,
                                        int lda, const u16* __restrict__ Bg,
                                        int ldb, int nkt, int wm, int wn,
                                        int l15, int l4, int tid,
                                        f32x4 acc[4][4]) {
    bf16x8 a[4][2], b[4][2];
    u16* A0 = lds;          u16* B0 = lds + 8192;
    u16* A1 = lds + 16384;  u16* B1 = lds + 24576;
    stg4(Ag, lda, A0, tid);      stg4(Bg, ldb, B0, tid);
    stg4(Ag + 64, lda, A1, tid); stg4(Bg + 64, ldb, B1, tid);
    VMCNT8; BAR;   // A0,B0 complete; A1,B1 (8 loads) in flight
    for (int t = 0; t < nkt; t += 2) {
        {
            const int k2 = ((t + 2 < nkt) ? t + 2 : nkt - 1) * 64;
            rd4(A0, wm * 64, l15, l4, a);
            rd4(B0, wn * 64, l15, l4, b);
            BAR;
            __builtin_amdgcn_s_setprio(1);
#pragma unroll
            for (int kk = 0; kk < 2; kk++)
#pragma unroll
                for (int mi = 0; mi < 4; mi++)
#pragma unroll
                    for (int ni = 0; ni < 2; ni++)
                        acc[mi][ni] = mfma16(a[mi][kk], b[ni][kk], acc[mi][ni]);
            __builtin_amdgcn_s_setprio(0);
            LGKM0; BAR;
            stg4(Ag + k2, lda, A0, tid);
            stg4(Bg + k2, ldb, B0, tid);
            VMCNT8; BAR;
            __builtin_amdgcn_s_setprio(1);
#pragma unroll
            for (int kk = 0; kk < 2; kk++)
#pragma unroll
                for (int mi = 0; mi < 4; mi++)
#pragma unroll
                    for (int ni = 2; ni < 4; ni++)
                        acc[mi][ni] = mfma16(a[mi][kk], b[ni][kk], acc[mi][ni]);
            __builtin_amdgcn_s_setprio(0);
            BAR;
        }
        {
            const int k3 = ((t + 3 < nkt) ? t + 3 : nkt - 1) * 64;
            rd4(A1, wm * 64, l15, l4, a);
            rd4(B1, wn * 64, l15, l4, b);
            BAR;
            __builtin_amdgcn_s_setprio(1);
#pragma unroll
            for (int kk = 0; kk < 2; kk++)
#pragma unroll
                for (int mi = 0; mi < 4; mi++)
#pragma unroll
                    for (int ni = 0; ni < 2; ni++)
                        acc[mi][ni] = mfma16(a[mi][kk], b[ni][kk], acc[mi][ni]);
            __builtin_amdgcn_s_setprio(0);
            LGKM0; BAR;
            stg4(Ag + k3, lda, A1, tid);
            stg4(Bg + k3, ldb, B1, tid);
            VMCNT8; BAR;
            __builtin_amdgcn_s_setprio(1);
#pragma unroll
            for (int kk = 0; kk < 2; kk++)
#pragma unroll
                for (int mi = 0; mi < 4; mi++)
#pragma unroll
                    for (int ni = 2; ni < 4; ni++)
                        acc[mi][ni] = mfma16(a[mi][kk], b[ni][kk], acc[mi][ni]);
            __builtin_amdgcn_s_setprio(0);
            BAR;
        }
    }
    VMCNT0;
}

// ======================================================================
// QKV: round-12 exact. 256x192 tile, BK=64, 8 waves, per-wave 128x48,
// acc[8][3], 512 tiles = exactly 2 per block. V -> direct transposed store.
// ======================================================================
#define QKV_PH0(AU, BU, ANX0, ANX1, K1)                                      \
    rd4((AU), 0, l15, l4, a);                                                \
    rd3((BU), wn * 48, l15, l4, b);                                          \
    stg128(Ag + (K1), DIN, (ANX0), tid);                                     \
    stg128(Ag + (size_t)128 * DIN + (K1), DIN, (ANX1), tid);                 \
    BAR;                                                                     \
    __builtin_amdgcn_s_setprio(1);                                           \
    _Pragma("unroll") for (int kk = 0; kk < 2; kk++)                         \
    _Pragma("unroll") for (int mi = 0; mi < 4; mi++)                         \
    _Pragma("unroll") for (int ni = 0; ni < 3; ni++)                         \
        acc[mi][ni] = mfma16(a[mi][kk], b[ni][kk], acc[mi][ni]);             \
    __builtin_amdgcn_s_setprio(0);                                           \
    BAR;

#define QKV_PH1(AU, BCUR, K2)                                                \
    rd4((AU), 64, l15, l4, a);                                               \
    stg192(Bg + (K2), DIN, (BCUR), tid);                                     \
    VMCNT3; BAR;                                                             \
    __builtin_amdgcn_s_setprio(1);                                           \
    _Pragma("unroll") for (int kk = 0; kk < 2; kk++)                         \
    _Pragma("unroll") for (int mi = 0; mi < 4; mi++)                         \
    _Pragma("unroll") for (int ni = 0; ni < 3; ni++)                         \
        acc[4 + mi][ni] = mfma16(a[mi][kk], b[ni][kk], acc[4 + mi][ni]);     \
    __builtin_amdgcn_s_setprio(0);                                           \
    BAR;

__global__ __launch_bounds__(512) void qkv_gemm192(const u16* __restrict__ xb,
                                                   const u16* __restrict__ wb,
                                                   u16* __restrict__ qkv,
                                                   u16* __restrict__ vt) {
    extern __shared__ __align__(16) u16 lds[];
    const int tid = threadIdx.x, lane = tid & 63, wid = tid >> 6;
    const int wm = wid >> 2, wn = wid & 3;
    const int l15 = lane & 15, l4 = lane >> 4;

    u16* A00 = lds;          u16* A01 = lds + 8192;
    u16* A10 = lds + 16384;  u16* A11 = lds + 24576;
    u16* B0  = lds + 32768;  u16* B1  = lds + 45056;
    u16* Ar0 = lds + wm * 8192;
    u16* Ar1 = lds + 16384 + wm * 8192;

    for (int tile = blockIdx.x; tile < 512; tile += 256) {
        const int wg = (tile & 7) * 64 + (tile >> 3);  // bijective XCD swizzle
        const int mt = wg & 31, nt = wg >> 5;
        const int m0 = mt * 256, n0 = nt * 192;
        const u16* Ag = xb + (size_t)m0 * DIN;
        const u16* Bg = wb + (size_t)n0 * DIN;
        f32x4 acc[8][3] = {};
        bf16x8 a[4][2], b[3][2];

        stg128(Ag, DIN, A00, tid);
        stg128(Ag + (size_t)128 * DIN, DIN, A01, tid);
        stg192(Bg, DIN, B0, tid);
        stg192(Bg + 64, DIN, B1, tid);
        VMCNT3;
        BAR;

        for (int i = 0; i < 8; i++) {
            const int k1 = (2 * i + 1) * 64;
            const int k2 = ((2 * i + 2 < 16) ? 2 * i + 2 : 15) * 64;
            const int k3 = ((2 * i + 3 < 16) ? 2 * i + 3 : 15) * 64;
            QKV_PH0(Ar0, B0, A10, A11, k1)
            QKV_PH1(Ar0, B0, k2)
            QKV_PH0(Ar1, B1, A00, A01, k2)
            QKV_PH1(Ar1, B1, k3)
        }
        VMCNT0;

#pragma unroll
        for (int ai = 0; ai < 8; ai++)
#pragma unroll
            for (int bj = 0; bj < 3; bj++) {
                const int colb = n0 + wn * 48 + bj * 16;   // 16-aligned, uniform
                const int row = m0 + wm * 128 + ai * 16 + l4 * 4;
                if (colb >= 2 * DOUT) {
                    int d = colb + l15 - 2 * DOUT;
                    int batch = row >> 11, s0 = row & 2047;
                    uint2 o;
                    o.x = (unsigned)f2bf(acc[ai][bj][0]) |
                          ((unsigned)f2bf(acc[ai][bj][1]) << 16);
                    o.y = (unsigned)f2bf(acc[ai][bj][2]) |
                          ((unsigned)f2bf(acc[ai][bj][3]) << 16);
                    *(uint2*)&vt[(size_t)batch * DOUT * SEQ + (size_t)d * SEQ + s0] = o;
                } else {
                    const int wsel = colb >> 10;
                    u16* Op = qkv + (size_t)wsel * ((size_t)BATCH * SEQ * DOUT);
                    const int col = (colb & 1023) + l15;
#pragma unroll
                    for (int rr = 0; rr < 4; rr++)
                        Op[(size_t)(row + rr) * DOUT + col] = f2bf(acc[ai][bj][rr]);
                }
            }
    }
}

// ---------------- QK^T + fused exp/row-sum (4-wave G4, triangular) ---------
__global__ __launch_bounds__(256) void qk4(const u16* __restrict__ qg,
                                           const u16* __restrict__ kg,
                                           u16* __restrict__ sg,
                                           float* __restrict__ rowsum) {
    extern __shared__ __align__(16) u16 lds[];
    const int bxx = blockIdx.x, batch = blockIdx.y;
    int mt = 0, base = 0;
#pragma unroll 16
    for (int m = 0; m < 16; m++) {
        int c = m + 1;
        if (bxx < base + c) { mt = m; break; }
        base += c;
    }
    const int nt = bxx - base;
    const int m0 = mt * 128, n0 = nt * 128;
    const int tid = threadIdx.x, lane = tid & 63, wid = tid >> 6;
    const int wm = wid >> 1, wn = wid & 1;
    const int l15 = lane & 15, l4 = lane >> 4;
    const size_t bo = (size_t)batch * SEQ * DOUT;

    f32x4 acc[4][4] = {};
    g4_body(lds, qg + bo + (size_t)m0 * DOUT, DOUT,
            kg + bo + (size_t)n0 * DOUT, DOUT, 16,
            wm, wn, l15, l4, tid, acc);

    u16* Sp = sg + (size_t)batch * SEQ * SEQ;
    float* Rs = rowsum + (size_t)batch * SEQ;
#pragma unroll
    for (int ai = 0; ai < 4; ai++)
#pragma unroll
        for (int rr = 0; rr < 4; rr++) {
            int q = m0 + wm * 64 + ai * 16 + l4 * 4 + rr;
            float rp = 0.f;
#pragma unroll
            for (int bj = 0; bj < 4; bj++) {
                int kc = n0 + wn * 64 + bj * 16 + l15;
                float p = (kc <= q) ? __expf(acc[ai][bj][rr] * SCALE) : 0.f;
                rp += p;
                Sp[(size_t)q * SEQ + kc] = f2bf(p);
            }
#pragma unroll
            for (int off = 8; off >= 1; off >>= 1) rp += __shfl_xor(rp, off, 16);
            if (l15 == 0) atomicAdd(&Rs[q], rp);
        }
}

// ---------------- PV: 4-wave G4, 512 blocks, complement-paired mt ----------
__global__ __launch_bounds__(256) void pv4(const u16* __restrict__ pg,
                                           const u16* __restrict__ vtg,
                                           const float* __restrict__ rowsum,
                                           float* __restrict__ og) {
    extern __shared__ __align__(16) u16 lds[];
    // blocks i and i+256 land on the same XCD/CU slot; mt + mt' = 15 ->
    // every CU's two co-resident blocks sum to exactly 34 K-steps.
    const int mt = (blockIdx.z < 2) ? (15 - (int)blockIdx.x) : (int)blockIdx.x;
    const int n0 = blockIdx.y * 128, batch = blockIdx.z;
    const int m0 = mt * 128;
    const int nkt = (mt + 1) * 2;
    const int tid = threadIdx.x, lane = tid & 63, wid = tid >> 6;
    const int wm = wid >> 1, wn = wid & 1;
    const int l15 = lane & 15, l4 = lane >> 4;
    const u16* Pb = pg + (size_t)batch * SEQ * SEQ;
    const u16* Vb = vtg + (size_t)batch * DOUT * SEQ + (size_t)n0 * SEQ;
    const float* Rs = rowsum + (size_t)batch * SEQ;
    float* Ob = og + (size_t)batch * SEQ * DOUT;

    f32x4 acc[4][4] = {};
    g4_body(lds, Pb + (size_t)m0 * SEQ, SEQ, Vb, SEQ, nkt,
            wm, wn, l15, l4, tid, acc);

#pragma unroll
    for (int ai = 0; ai < 4; ai++)
#pragma unroll
        for (int rr = 0; rr < 4; rr++) {
            int q = m0 + wm * 64 + ai * 16 + l4 * 4 + rr;
            float inv = 1.0f / Rs[q];
#pragma unroll
            for (int bj = 0; bj < 4; bj++) {
                int d = n0 + wn * 64 + bj * 16 + l15;
                Ob[(size_t)q * DOUT + d] = acc[ai][bj][rr] * inv;
            }
        }
}

extern "C" void kernel_launch(void* const* d_in, const int* in_sizes, int n_in,
                              void* d_out, int out_size, void* d_ws, size_t ws_size,
                              hipStream_t stream) {
    const float* x  = (const float*)d_in[0];
    const float* wq = (const float*)d_in[1];
    const float* wk = (const float*)d_in[2];
    const float* wv = (const float*)d_in[3];
    float* out = (float*)d_out;

    const size_t NX  = (size_t)BATCH * SEQ * DIN;  // 8M elems
    const size_t NWT = (size_t)DOUT * DIN;         // 1M elems
    u16* xb  = (u16*)d_ws;            // 16 MB
    u16* wb  = xb + NX;               // 6 MB (wq|wk|wv = Wcat[3072][1024])
    u16* qkv = wb + 3 * NWT;          // 48 MB (q,k; v slot unused)
    u16* vt  = qkv + 3 * NX;          // 16 MB (V^T, written directly by qkv)
    u16* sb  = vt + NX;               // 33.5 MB P' (bf16)
    float* rowsum = (float*)(sb + (size_t)BATCH * SEQ * SEQ);  // 32 KB

    cvt_all<<<(NX + 3 * NWT) / 8 / 256, 256, 0, stream>>>(x, wq, wk, wv, xb, rowsum);

    (void)hipFuncSetAttribute((const void*)qkv_gemm192,
                              hipFuncAttributeMaxDynamicSharedMemorySize, 114688);
    (void)hipFuncSetAttribute((const void*)qk4,
                              hipFuncAttributeMaxDynamicSharedMemorySize, 65536);
    (void)hipFuncSetAttribute((const void*)pv4,
                              hipFuncAttributeMaxDynamicSharedMemorySize, 65536);

    qkv_gemm192<<<dim3(256), dim3(512), 114688, stream>>>(xb, wb, qkv, vt);

    qk4<<<dim3(136, BATCH), dim3(256), 65536, stream>>>(qkv, qkv + NX, sb, rowsum);

    pv4<<<dim3(16, 8, 4), dim3(256), 65536, stream>>>(sb, vt, rowsum, out);
}